// Round 2
// baseline (455.524 us; speedup 1.0000x reference)
//
#include <hip/hip_runtime.h>

// QuadNeighborhoodEncoderDeepsets on gfx950 — round 5.
// Occupancy attack: round-4 was 2 waves/SIMD (Bf[8][4]=128 regs for W2^T
// -> ~256 unified regs/wave). Restructure to 1024-thread blocks, 16 waves
// x 16 output cols each: Bf[8][1]=32 regs, acc[3][1], per-wave regs ~110
// -> __launch_bounds__(1024,4) = 4 waves/SIMD (2x occupancy). Same total
// MFMA/tanh/LDS work, 4x more waves to hide LDS/global/barrier latency.
// Mean phase remapped to col = 16*wave + c16 (2 batches per q-group) so
// each lane reads only its own wave's ht cols -> still no barrier there.

#define HID     256
#define OBSD    54
#define SELFD   18
#define TILE_B  8
#define TILE_R  48            // 8 batches * 6 neighbors
#define LDA     264           // A-tile row stride (shorts), 16B-aligned rows
#define LDH     54            // hT col stride (shorts): 27 dwords (odd -> spread)
#define BATCHN  131072
#define NTILES  (BATCHN / TILE_B)
#define GRID_WG 2048
#define TANH_K  2.8853900817779268f   // 2/ln2

typedef __attribute__((ext_vector_type(8))) short bf16x8;   // 4 VGPRs
typedef __attribute__((ext_vector_type(4))) float f32x4;

// pack two f32 -> one dword of 2 bf16 (RNE), single VALU op
__device__ __forceinline__ unsigned cvt_pk_bf16(float lo, float hi) {
    unsigned r;
    asm("v_cvt_pk_bf16_f32 %0, %1, %2" : "=v"(r) : "v"(lo), "v"(hi));
    return r;
}

// tanh(x+b) = 1 - 2/(exp2((x+b)*2/ln2)+1), bias pre-scaled by 2/ln2:
// fma + exp2 + add + rcp + fma  (3 VALU + 2 trans)
__device__ __forceinline__ float tanh_fused(float x, float bK) {
    float t = __builtin_amdgcn_exp2f(__builtin_fmaf(x, TANH_K, bK));
    return 1.0f - 2.0f * __builtin_amdgcn_rcpf(t + 1.0f);
}

// fp32 -> bf16 bits (RNE) — prep kernel only
__device__ __forceinline__ unsigned bfbits(float f) {
    unsigned u = __float_as_uint(f);
    u += 0x7fffu + ((u >> 16) & 1u);
    return u >> 16;
}

// w2t[n][k] = bf16(W2[k][n])  (256x256)
// w1t[n][k] = k<6 ? bf16(W1[k][n]) : 0   (256x32, K zero-padded)
__global__ void prep(const float* __restrict__ W1, const float* __restrict__ W2,
                     short* __restrict__ w1t, short* __restrict__ w2t) {
    int idx = blockIdx.x * 256 + threadIdx.x;
    if (idx < 65536) {
        int n = idx >> 8, k = idx & 255;
        w2t[idx] = (short)bfbits(W2[k * HID + n]);
    } else {
        int j = idx - 65536;
        int n = j >> 5, k = j & 31;
        w1t[j] = (k < 6) ? (short)bfbits(W1[k * HID + n]) : (short)0;
    }
}

__global__ __launch_bounds__(1024, 4) void qenc_main(
        const float* __restrict__ obs,
        const short* __restrict__ w1t,
        const float* __restrict__ b1,
        const short* __restrict__ w2t,
        const float* __restrict__ b2,
        float* __restrict__ out)
{
    __shared__ union {
        short a[TILE_R * LDA];    // 25344 B : bf16 h1 (A-tile, row-major)
        short ht[HID * LDH];      // 27648 B : bf16 h2 transposed [col][row]
    } u;

    const int tid  = threadIdx.x;
    const int wave = tid >> 6;        // 0..15
    const int lane = tid & 63;
    const int q    = lane >> 4;
    const int c16  = lane & 15;
    const int colbase = wave * 16;    // this wave's 16-column slice

    // ---- persistent fragments / constants (loaded once per workgroup) ----
    // B layout for 16x16x32: lane holds B[k=q*8+j][n=lane&15].
    bf16x8 Bf[8];                     // W2^T slice: 32 regs
    #pragma unroll
    for (int kk = 0; kk < 8; ++kk)
        Bf[kk] = *(const bf16x8*)(w2t + (colbase + c16) * HID + kk * 32 + q * 8);

    // W1^T frag (A-operand of swapped layer-1 MFMA): 4 regs, persistent
    bf16x8 B1f = *(const bf16x8*)(w1t + (colbase + c16) * 32 + q * 8);

    // layer-1 swapped-MFMA: lane's 4 output cols are colbase + q*4 + g
    float b1s[4];
    #pragma unroll
    for (int g = 0; g < 4; ++g)
        b1s[g] = b1[colbase + q * 4 + g] * TANH_K;
    // epilogue col = colbase + c16
    const float b2s = b2[colbase + c16] * TANH_K;

    // per-lane x source offsets (constant across tiles): row = rt*16+c16
    int soff[3];
    #pragma unroll
    for (int rt = 0; rt < 3; ++rt) {
        int row = rt * 16 + c16;
        soff[rt] = (row / 6) * OBSD + SELFD + (row % 6) * 6;
    }

    for (int tile = blockIdx.x; tile < NTILES; tile += GRID_WG) {
        const size_t obase = (size_t)tile * (TILE_B * OBSD);

        // ---- layer 1: h1 = tanh(x @ W1 + b1), swapped operands ----
        // mfma(W1T-as-A, x-as-B): D[m=h1col][n=h1row]; lane holds
        // row = rt*16+c16, cols = colbase + q*4 + g  (4 consecutive)
        #pragma unroll
        for (int rt = 0; rt < 3; ++rt) {
            // every lane loads its row's 6 floats (q- and wave-redundant;
            // 1.7KB tile, L1-hot). k>=6 multiplies w1t's zero rows, so the
            // q>0 lanes' duplicate data contributes exactly zero.
            const float* src = obs + obase + soff[rt];
            float2 f0 = *(const float2*)(src);
            float2 f1 = *(const float2*)(src + 2);
            float2 f2 = *(const float2*)(src + 4);
            union { unsigned w[4]; bf16x8 v; } xf;
            xf.w[0] = cvt_pk_bf16(f0.x, f0.y);
            xf.w[1] = cvt_pk_bf16(f1.x, f1.y);
            xf.w[2] = cvt_pk_bf16(f2.x, f2.y);
            xf.w[3] = 0u;
            f32x4 c = __builtin_amdgcn_mfma_f32_16x16x32_bf16(
                B1f, xf.v, (f32x4){0.f, 0.f, 0.f, 0.f}, 0, 0, 0);
            float t0 = tanh_fused(c[0], b1s[0]);
            float t1 = tanh_fused(c[1], b1s[1]);
            float t2 = tanh_fused(c[2], b1s[2]);
            float t3 = tanh_fused(c[3], b1s[3]);
            uint2 dd;
            dd.x = cvt_pk_bf16(t0, t1);
            dd.y = cvt_pk_bf16(t2, t3);
            // row-major A-tile, 4 consecutive cols -> one 8B store
            *(uint2*)&u.a[(rt * 16 + c16) * LDA + colbase + q * 4] = dd;
        }
        __syncthreads();

        // ---- layer 2: (48x256)@(256x16 slice), B in regs ----
        f32x4 acc[3];
        #pragma unroll
        for (int rt = 0; rt < 3; ++rt) acc[rt] = (f32x4){0.f, 0.f, 0.f, 0.f};

        #pragma unroll
        for (int kk = 0; kk < 8; ++kk) {
            bf16x8 Af[3];   // A layout: lane holds A[m=lane&15][k=q*8+j]
            #pragma unroll
            for (int rt = 0; rt < 3; ++rt)
                Af[rt] = *(const bf16x8*)&u.a[(rt * 16 + c16) * LDA + kk * 32 + q * 8];
            #pragma unroll
            for (int rt = 0; rt < 3; ++rt)
                acc[rt] = __builtin_amdgcn_mfma_f32_16x16x32_bf16(
                    Af[rt], Bf[kk], acc[rt], 0, 0, 0);
        }
        __syncthreads();   // A-tile reads done before aliased ht writes

        // ---- epilogue: tanh -> bf16, transposed [col][row], packed dwords
        // C layout: col = colbase + c16, row = rt*16 + q*4 + g
        {
            const int col = colbase + c16;
            #pragma unroll
            for (int rt = 0; rt < 3; ++rt) {
                float t0 = tanh_fused(acc[rt][0], b2s);
                float t1 = tanh_fused(acc[rt][1], b2s);
                float t2 = tanh_fused(acc[rt][2], b2s);
                float t3 = tanh_fused(acc[rt][3], b2s);
                const int row = rt * 16 + q * 4;   // even -> dword-aligned
                *(unsigned*)&u.ht[col * LDH + row]     = cvt_pk_bf16(t0, t1);
                *(unsigned*)&u.ht[col * LDH + row + 2] = cvt_pk_bf16(t2, t3);
            }
        }
        // NO barrier: lane reads col = colbase + c16, which its own wave
        // fully wrote (all 48 rows); in-wave LDS ordering suffices.

        // ---- mean over 6 neighbors: lane owns col = colbase+c16,
        // q-group handles batches 2q and 2q+1 (3 dwords each)
        const int b0 = tile * TILE_B;
        {
            const int col = colbase + c16;
            #pragma unroll
            for (int jj = 0; jj < 2; ++jj) {
                const int bl = q * 2 + jj;
                const unsigned* p = (const unsigned*)&u.ht[col * LDH + bl * 6];
                float s = 0.f;
                #pragma unroll
                for (int d = 0; d < 3; ++d) {
                    unsigned uu = p[d];
                    s += __uint_as_float(uu << 16) + __uint_as_float(uu & 0xffff0000u);
                }
                out[(size_t)(b0 + bl) * HID + col] = s * (1.0f / 6.0f);
            }
        }
        __syncthreads();   // protect union reuse (next tile's u.a writes)
    }
}

extern "C" void kernel_launch(void* const* d_in, const int* in_sizes, int n_in,
                              void* d_out, int out_size, void* d_ws, size_t ws_size,
                              hipStream_t stream) {
    // inputs: 0 self_obs (unused), 1 obs, 2 W1, 3 b1, 4 W2, 5 b2, 6/7 scalars
    const float* obs = (const float*)d_in[1];
    const float* W1  = (const float*)d_in[2];
    const float* b1  = (const float*)d_in[3];
    const float* W2  = (const float*)d_in[4];
    const float* b2  = (const float*)d_in[5];
    float* outp = (float*)d_out;

    short* w2t = (short*)d_ws;                       // 131072 B
    short* w1t = (short*)((char*)d_ws + 131072);     // 16384 B

    prep<<<288, 256, 0, stream>>>(W1, W2, w1t, w2t);
    qenc_main<<<GRID_WG, 1024, 0, stream>>>(obs, w1t, b1, w2t, b2, outp);
}

// Round 4
// 337.720 us; speedup vs baseline: 1.3488x; 1.3488x over previous
//
#include <hip/hip_runtime.h>

// QuadNeighborhoodEncoderDeepsets on gfx950 — round 7.
// Round-6 post-mortem: de-union + rt-fused epilogue + dropped barrier
// produced stale-LDS garbage (absmax 1.23, values ~468 = garbage bf16).
// Round 7 = round-4 dataflow VERBATIM (union'd LDS, 3 barriers/tile,
// separate epilogue phase, own-wave barrier-free mean) with only the
// occupancy geometry changed: 512 threads, 8 waves x 32 cols.
// Bf[8][2]=64 regs, acc[3][2]=24, peak live ~120 -> launch_bounds(512,4)
// = 4 waves/SIMD = 2 blocks/CU co-resident (round 4: 2 waves/SIMD;
// round 5's 1-block/CU barrier exposure avoided). A-read amplification
// only 2x round 4.

#define HID     256
#define OBSD    54
#define SELFD   18
#define TILE_B  8
#define TILE_R  48            // 8 batches * 6 neighbors
#define LDA     264           // A-tile row stride (shorts), 16B-aligned rows
#define LDH     54            // hT col stride (shorts): 27 dwords (odd -> spread)
#define BATCHN  131072
#define NTILES  (BATCHN / TILE_B)
#define GRID_WG 2048
#define TANH_K  2.8853900817779268f   // 2/ln2

typedef __attribute__((ext_vector_type(8))) short bf16x8;   // 4 VGPRs
typedef __attribute__((ext_vector_type(4))) float f32x4;

// pack two f32 -> one dword of 2 bf16 (RNE), single VALU op
__device__ __forceinline__ unsigned cvt_pk_bf16(float lo, float hi) {
    unsigned r;
    asm("v_cvt_pk_bf16_f32 %0, %1, %2" : "=v"(r) : "v"(lo), "v"(hi));
    return r;
}

// tanh(x+b) = 1 - 2/(exp2((x+b)*2/ln2)+1), bias pre-scaled by 2/ln2:
// fma + exp2 + add + rcp + fma  (3 VALU + 2 trans)
__device__ __forceinline__ float tanh_fused(float x, float bK) {
    float t = __builtin_amdgcn_exp2f(__builtin_fmaf(x, TANH_K, bK));
    return 1.0f - 2.0f * __builtin_amdgcn_rcpf(t + 1.0f);
}

// fp32 -> bf16 bits (RNE) — prep kernel only
__device__ __forceinline__ unsigned bfbits(float f) {
    unsigned u = __float_as_uint(f);
    u += 0x7fffu + ((u >> 16) & 1u);
    return u >> 16;
}

// w2t[n][k] = bf16(W2[k][n])  (256x256)
// w1t[n][k] = k<6 ? bf16(W1[k][n]) : 0   (256x32, K zero-padded)
__global__ void prep(const float* __restrict__ W1, const float* __restrict__ W2,
                     short* __restrict__ w1t, short* __restrict__ w2t) {
    int idx = blockIdx.x * 256 + threadIdx.x;
    if (idx < 65536) {
        int n = idx >> 8, k = idx & 255;
        w2t[idx] = (short)bfbits(W2[k * HID + n]);
    } else {
        int j = idx - 65536;
        int n = j >> 5, k = j & 31;
        w1t[j] = (k < 6) ? (short)bfbits(W1[k * HID + n]) : (short)0;
    }
}

__global__ __launch_bounds__(512, 4) void qenc_main(
        const float* __restrict__ obs,
        const short* __restrict__ w1t,
        const float* __restrict__ b1,
        const short* __restrict__ w2t,
        const float* __restrict__ b2,
        float* __restrict__ out)
{
    __shared__ union {
        short a[TILE_R * LDA];    // 25344 B : bf16 h1 (A-tile, row-major)
        short ht[HID * LDH];      // 27648 B : bf16 h2 transposed [col][row]
    } u;

    const int tid  = threadIdx.x;
    const int wave = tid >> 6;        // 0..7
    const int lane = tid & 63;
    const int q    = lane >> 4;
    const int c16  = lane & 15;
    const int colbase = wave * 32;    // this wave's 32-column slice

    // ---- persistent fragments / constants (loaded once per workgroup) ----
    // B layout for 16x16x32: lane holds B[k=q*8+j][n=lane&15].
    bf16x8 Bf[8][2];                  // W2^T slice: 64 regs
    #pragma unroll
    for (int kk = 0; kk < 8; ++kk)
        #pragma unroll
        for (int ct = 0; ct < 2; ++ct)
            Bf[kk][ct] = *(const bf16x8*)
                (w2t + (colbase + ct * 16 + c16) * HID + kk * 32 + q * 8);

    // W1^T frags (A-operand of swapped layer-1 MFMA): 8 regs
    bf16x8 B1f[2];
    #pragma unroll
    for (int ct = 0; ct < 2; ++ct)
        B1f[ct] = *(const bf16x8*)(w1t + (colbase + ct * 16 + c16) * 32 + q * 8);

    // layer-1 swapped-MFMA: lane's output cols are colbase + ct*16 + q*4 + g
    float b1s[2][4];
    #pragma unroll
    for (int ct = 0; ct < 2; ++ct)
        #pragma unroll
        for (int g = 0; g < 4; ++g)
            b1s[ct][g] = b1[colbase + ct * 16 + q * 4 + g] * TANH_K;
    // layer-2 epilogue col = colbase + ct*16 + c16
    float b2s[2];
    #pragma unroll
    for (int ct = 0; ct < 2; ++ct)
        b2s[ct] = b2[colbase + ct * 16 + c16] * TANH_K;

    // per-lane x source offsets (constant across tiles): row = rt*16+c16
    int soff[3];
    #pragma unroll
    for (int rt = 0; rt < 3; ++rt) {
        int row = rt * 16 + c16;
        soff[rt] = (row / 6) * OBSD + SELFD + (row % 6) * 6;
    }

    for (int tile = blockIdx.x; tile < NTILES; tile += GRID_WG) {
        const size_t obase = (size_t)tile * (TILE_B * OBSD);

        // ---- layer 1: h1 = tanh(x @ W1 + b1), swapped operands ----
        // mfma(W1T-as-A, x-as-B): lane holds rows = rt*16+c16,
        // cols = colbase + ct*16 + q*4 + g  (4 consecutive -> 8B store)
        #pragma unroll
        for (int rt = 0; rt < 3; ++rt) {
            // every lane loads its row's 6 floats (q/wave-redundant, L1-hot);
            // k>=6 multiplies w1t's zero rows -> contributes exactly zero.
            const float* src = obs + obase + soff[rt];
            float2 f0 = *(const float2*)(src);
            float2 f1 = *(const float2*)(src + 2);
            float2 f2 = *(const float2*)(src + 4);
            union { unsigned w[4]; bf16x8 v; } xf;
            xf.w[0] = cvt_pk_bf16(f0.x, f0.y);
            xf.w[1] = cvt_pk_bf16(f1.x, f1.y);
            xf.w[2] = cvt_pk_bf16(f2.x, f2.y);
            xf.w[3] = 0u;
            #pragma unroll
            for (int ct = 0; ct < 2; ++ct) {
                f32x4 c = __builtin_amdgcn_mfma_f32_16x16x32_bf16(
                    B1f[ct], xf.v, (f32x4){0.f, 0.f, 0.f, 0.f}, 0, 0, 0);
                float t0 = tanh_fused(c[0], b1s[ct][0]);
                float t1 = tanh_fused(c[1], b1s[ct][1]);
                float t2 = tanh_fused(c[2], b1s[ct][2]);
                float t3 = tanh_fused(c[3], b1s[ct][3]);
                uint2 dd;
                dd.x = cvt_pk_bf16(t0, t1);
                dd.y = cvt_pk_bf16(t2, t3);
                // row-major A-tile, 4 consecutive cols -> one 8B store
                *(uint2*)&u.a[(rt * 16 + c16) * LDA + colbase + ct * 16 + q * 4] = dd;
            }
        }
        __syncthreads();   // all waves' h1 cols visible before layer 2

        // ---- layer 2: (48x256)@(256x32 slice), B in regs ----
        f32x4 acc[3][2];
        #pragma unroll
        for (int rt = 0; rt < 3; ++rt)
            #pragma unroll
            for (int ct = 0; ct < 2; ++ct) acc[rt][ct] = (f32x4){0.f, 0.f, 0.f, 0.f};

        #pragma unroll
        for (int kk = 0; kk < 8; ++kk) {
            bf16x8 Af[3];   // A layout: lane holds A[m=lane&15][k=q*8+j]
            #pragma unroll
            for (int rt = 0; rt < 3; ++rt)
                Af[rt] = *(const bf16x8*)&u.a[(rt * 16 + c16) * LDA + kk * 32 + q * 8];
            #pragma unroll
            for (int rt = 0; rt < 3; ++rt)
                #pragma unroll
                for (int ct = 0; ct < 2; ++ct)
                    acc[rt][ct] = __builtin_amdgcn_mfma_f32_16x16x32_bf16(
                        Af[rt], Bf[kk][ct], acc[rt][ct], 0, 0, 0);
        }
        __syncthreads();   // A-tile reads done before aliased ht writes

        // ---- epilogue: tanh -> bf16, transposed [col][row], packed dwords
        // C layout: col = colbase + ct*16 + c16, row = rt*16 + q*4 + g
        #pragma unroll
        for (int ct = 0; ct < 2; ++ct) {
            const int col = colbase + ct * 16 + c16;
            #pragma unroll
            for (int rt = 0; rt < 3; ++rt) {
                float t0 = tanh_fused(acc[rt][ct][0], b2s[ct]);
                float t1 = tanh_fused(acc[rt][ct][1], b2s[ct]);
                float t2 = tanh_fused(acc[rt][ct][2], b2s[ct]);
                float t3 = tanh_fused(acc[rt][ct][3], b2s[ct]);
                const int row = rt * 16 + q * 4;   // even -> dword-aligned
                *(unsigned*)&u.ht[col * LDH + row]     = cvt_pk_bf16(t0, t1);
                *(unsigned*)&u.ht[col * LDH + row + 2] = cvt_pk_bf16(t2, t3);
            }
        }
        // NO barrier: mean reads only cols this wave wrote (all 48 rows of
        // cols colbase..colbase+31); in-wave LDS program order suffices
        // (same pattern as passing rounds 4/5).

        // ---- mean over 6 neighbors ----
        // lane owns col = colbase + (lane&31); half-wave handles 4 batches
        const int b0 = tile * TILE_B;
        {
            const int col = colbase + (lane & 31);
            const int bl0 = (lane >> 5) * 4;
            #pragma unroll
            for (int jj = 0; jj < 4; ++jj) {
                const int bl = bl0 + jj;
                const unsigned* p = (const unsigned*)&u.ht[col * LDH + bl * 6];
                float s = 0.f;
                #pragma unroll
                for (int d = 0; d < 3; ++d) {
                    unsigned uu = p[d];
                    s += __uint_as_float(uu << 16) + __uint_as_float(uu & 0xffff0000u);
                }
                out[(size_t)(b0 + bl) * HID + col] = s * (1.0f / 6.0f);
            }
        }
        __syncthreads();   // all ht-reads done before next tile's u.a writes
    }
}

extern "C" void kernel_launch(void* const* d_in, const int* in_sizes, int n_in,
                              void* d_out, int out_size, void* d_ws, size_t ws_size,
                              hipStream_t stream) {
    // inputs: 0 self_obs (unused), 1 obs, 2 W1, 3 b1, 4 W2, 5 b2, 6/7 scalars
    const float* obs = (const float*)d_in[1];
    const float* W1  = (const float*)d_in[2];
    const float* b1  = (const float*)d_in[3];
    const float* W2  = (const float*)d_in[4];
    const float* b2  = (const float*)d_in[5];
    float* outp = (float*)d_out;

    short* w2t = (short*)d_ws;                       // 131072 B
    short* w1t = (short*)((char*)d_ws + 131072);     // 16384 B

    prep<<<288, 256, 0, stream>>>(W1, W2, w1t, w2t);
    qenc_main<<<GRID_WG, 512, 0, stream>>>(obs, w1t, b1, w2t, b2, outp);
}

// Round 5
// 335.074 us; speedup vs baseline: 1.3595x; 1.0079x over previous
//
#include <hip/hip_runtime.h>

// QuadNeighborhoodEncoderDeepsets on gfx950 — round 8.
// r7 post-mortem: occupancy 2x (21->42%) bought only 2% — kernel is
// work-volume-bound across VALU/LDS/MFMA pipes, not latency-bound. Biggest
// removable work: the h2 -> LDS(ht) -> bf16-unpack -> mean roundtrip
// (24 LDS ops + ~60 VALU/thread/tile). Round 8 folds the neighbor-mean
// into registers: each batch's 6 rows live in exactly 2 adjacent q-groups;
// one shfl_xor(16) + one shfl_xor(48) with asymmetric payloads complete
// all 8 batch sums (verified lane-by-lane: q0 owns bl0,bl5; q1: bl3,bl6;
// q2: bl4,bl1; q3: bl7,bl2). ht + union + mean phase deleted; f32 mean
// (better numerics). Same 2-barrier structure as passing r7.

#define HID     256
#define OBSD    54
#define SELFD   18
#define TILE_B  8
#define TILE_R  48            // 8 batches * 6 neighbors
#define LDA     264           // A-tile row stride (shorts), 16B-aligned rows
#define BATCHN  131072
#define NTILES  (BATCHN / TILE_B)
#define GRID_WG 2048
#define TANH_K  2.8853900817779268f   // 2/ln2

typedef __attribute__((ext_vector_type(8))) short bf16x8;   // 4 VGPRs
typedef __attribute__((ext_vector_type(4))) float f32x4;

// pack two f32 -> one dword of 2 bf16 (RNE), single VALU op
__device__ __forceinline__ unsigned cvt_pk_bf16(float lo, float hi) {
    unsigned r;
    asm("v_cvt_pk_bf16_f32 %0, %1, %2" : "=v"(r) : "v"(lo), "v"(hi));
    return r;
}

// tanh(x+b) = 1 - 2/(exp2((x+b)*2/ln2)+1), bias pre-scaled by 2/ln2:
// fma + exp2 + add + rcp + fma  (3 VALU + 2 trans)
__device__ __forceinline__ float tanh_fused(float x, float bK) {
    float t = __builtin_amdgcn_exp2f(__builtin_fmaf(x, TANH_K, bK));
    return 1.0f - 2.0f * __builtin_amdgcn_rcpf(t + 1.0f);
}

// fp32 -> bf16 bits (RNE) — prep kernel only
__device__ __forceinline__ unsigned bfbits(float f) {
    unsigned u = __float_as_uint(f);
    u += 0x7fffu + ((u >> 16) & 1u);
    return u >> 16;
}

// w2t[n][k] = bf16(W2[k][n])  (256x256)
// w1t[n][k] = k<6 ? bf16(W1[k][n]) : 0   (256x32, K zero-padded)
__global__ void prep(const float* __restrict__ W1, const float* __restrict__ W2,
                     short* __restrict__ w1t, short* __restrict__ w2t) {
    int idx = blockIdx.x * 256 + threadIdx.x;
    if (idx < 65536) {
        int n = idx >> 8, k = idx & 255;
        w2t[idx] = (short)bfbits(W2[k * HID + n]);
    } else {
        int j = idx - 65536;
        int n = j >> 5, k = j & 31;
        w1t[j] = (k < 6) ? (short)bfbits(W1[k * HID + n]) : (short)0;
    }
}

__global__ __launch_bounds__(512, 4) void qenc_main(
        const float* __restrict__ obs,
        const short* __restrict__ w1t,
        const float* __restrict__ b1,
        const short* __restrict__ w2t,
        const float* __restrict__ b2,
        float* __restrict__ out)
{
    __shared__ short a[TILE_R * LDA];     // 25344 B : bf16 h1 (A-tile)

    const int tid  = threadIdx.x;
    const int wave = tid >> 6;        // 0..7
    const int lane = tid & 63;
    const int q    = lane >> 4;
    const int c16  = lane & 15;
    const int colbase = wave * 32;    // this wave's 32-column slice

    // ---- persistent fragments / constants (loaded once per workgroup) ----
    // B layout for 16x16x32: lane holds B[k=q*8+j][n=lane&15].
    bf16x8 Bf[8][2];                  // W2^T slice: 64 regs
    #pragma unroll
    for (int kk = 0; kk < 8; ++kk)
        #pragma unroll
        for (int ct = 0; ct < 2; ++ct)
            Bf[kk][ct] = *(const bf16x8*)
                (w2t + (colbase + ct * 16 + c16) * HID + kk * 32 + q * 8);

    // W1^T frags (A-operand of swapped layer-1 MFMA): 8 regs
    bf16x8 B1f[2];
    #pragma unroll
    for (int ct = 0; ct < 2; ++ct)
        B1f[ct] = *(const bf16x8*)(w1t + (colbase + ct * 16 + c16) * 32 + q * 8);

    // layer-1 swapped-MFMA: lane's output cols are colbase + ct*16 + q*4 + g
    float b1s[2][4];
    #pragma unroll
    for (int ct = 0; ct < 2; ++ct)
        #pragma unroll
        for (int g = 0; g < 4; ++g)
            b1s[ct][g] = b1[colbase + ct * 16 + q * 4 + g] * TANH_K;
    // layer-2 epilogue col = colbase + ct*16 + c16
    float b2s[2];
    #pragma unroll
    for (int ct = 0; ct < 2; ++ct)
        b2s[ct] = b2[colbase + ct * 16 + c16] * TANH_K;

    // per-lane x source offsets (constant across tiles): row = rt*16+c16
    int soff[3];
    #pragma unroll
    for (int rt = 0; rt < 3; ++rt) {
        int row = rt * 16 + c16;
        soff[rt] = (row / 6) * OBSD + SELFD + (row % 6) * 6;
    }

    // register-mean routing (q-only, precomputed):
    // lane q owns batches blA = {0,3,4,7}[q] and blB = {5,6,1,2}[q]
    const int blA = 2 * q + (q & 1);              // 0,3,4,7
    const int blB = (q < 2) ? (q + 5) : (q - 1);  // 5,6,1,2
    const bool isq0 = (q == 0), isq1 = (q == 1), isq2 = (q == 2);

    for (int tile = blockIdx.x; tile < NTILES; tile += GRID_WG) {
        const size_t obase = (size_t)tile * (TILE_B * OBSD);

        // ---- layer 1: h1 = tanh(x @ W1 + b1), swapped operands ----
        // mfma(W1T-as-A, x-as-B): lane holds rows = rt*16+c16,
        // cols = colbase + ct*16 + q*4 + g  (4 consecutive -> 8B store)
        #pragma unroll
        for (int rt = 0; rt < 3; ++rt) {
            // every lane loads its row's 6 floats (q/wave-redundant, L1-hot);
            // k>=6 multiplies w1t's zero rows -> contributes exactly zero.
            const float* src = obs + obase + soff[rt];
            float2 f0 = *(const float2*)(src);
            float2 f1 = *(const float2*)(src + 2);
            float2 f2 = *(const float2*)(src + 4);
            union { unsigned w[4]; bf16x8 v; } xf;
            xf.w[0] = cvt_pk_bf16(f0.x, f0.y);
            xf.w[1] = cvt_pk_bf16(f1.x, f1.y);
            xf.w[2] = cvt_pk_bf16(f2.x, f2.y);
            xf.w[3] = 0u;
            #pragma unroll
            for (int ct = 0; ct < 2; ++ct) {
                f32x4 c = __builtin_amdgcn_mfma_f32_16x16x32_bf16(
                    B1f[ct], xf.v, (f32x4){0.f, 0.f, 0.f, 0.f}, 0, 0, 0);
                float t0 = tanh_fused(c[0], b1s[ct][0]);
                float t1 = tanh_fused(c[1], b1s[ct][1]);
                float t2 = tanh_fused(c[2], b1s[ct][2]);
                float t3 = tanh_fused(c[3], b1s[ct][3]);
                uint2 dd;
                dd.x = cvt_pk_bf16(t0, t1);
                dd.y = cvt_pk_bf16(t2, t3);
                // row-major A-tile, 4 consecutive cols -> one 8B store
                *(uint2*)&a[(rt * 16 + c16) * LDA + colbase + ct * 16 + q * 4] = dd;
            }
        }
        __syncthreads();   // all waves' h1 cols visible before layer 2

        // ---- layer 2: (48x256)@(256x32 slice), B in regs ----
        f32x4 acc[3][2];
        #pragma unroll
        for (int rt = 0; rt < 3; ++rt)
            #pragma unroll
            for (int ct = 0; ct < 2; ++ct) acc[rt][ct] = (f32x4){0.f, 0.f, 0.f, 0.f};

        #pragma unroll
        for (int kk = 0; kk < 8; ++kk) {
            bf16x8 Af[3];   // A layout: lane holds A[m=lane&15][k=q*8+j]
            #pragma unroll
            for (int rt = 0; rt < 3; ++rt)
                Af[rt] = *(const bf16x8*)&a[(rt * 16 + c16) * LDA + kk * 32 + q * 8];
            #pragma unroll
            for (int rt = 0; rt < 3; ++rt)
                #pragma unroll
                for (int ct = 0; ct < 2; ++ct)
                    acc[rt][ct] = __builtin_amdgcn_mfma_f32_16x16x32_bf16(
                        Af[rt], Bf[kk][ct], acc[rt][ct], 0, 0, 0);
        }

        // ---- fused epilogue: tanh -> register-space neighbor mean ----
        // C layout: col = colbase + ct*16 + c16, row = rt*16 + q*4 + g.
        // Lane's 12 rows per ct group into batch partials:
        //   s[rt] = t0+t1, u[rt] = t2+t3, f[rt] = s+u
        //   q0: A=f0(bl0) B=s1(bl2) C=u1(bl3) D=f2(bl5)
        //   q1: A=s0(bl0) B=u0(bl1) C=f1(bl3) D=f2(bl6)
        //   q2: A=f0(bl1) B=f1(bl4) C=s2(bl6) D=u2(bl7)
        //   q3: A=f0(bl2) B=s1(bl4) C=u1(bl5) D=f2(bl7)
        // Pairs (xor16): (q0,q1)->{bl0,bl3}, (q2,q3)->{bl4,bl7}
        // Pairs (xor48): (q1,q2)->{bl1,bl6}, (q3,q0)->{bl2,bl5}
        const int b0 = tile * TILE_B;
        #pragma unroll
        for (int ct = 0; ct < 2; ++ct) {
            const int col = colbase + ct * 16 + c16;
            float s[3], uu[3], f[3];
            #pragma unroll
            for (int rt = 0; rt < 3; ++rt) {
                float t0 = tanh_fused(acc[rt][ct][0], b2s[ct]);
                float t1 = tanh_fused(acc[rt][ct][1], b2s[ct]);
                float t2 = tanh_fused(acc[rt][ct][2], b2s[ct]);
                float t3 = tanh_fused(acc[rt][ct][3], b2s[ct]);
                s[rt] = t0 + t1; uu[rt] = t2 + t3; f[rt] = s[rt] + uu[rt];
            }
            float A = isq1 ? s[0] : f[0];
            float B = isq1 ? uu[0] : (isq2 ? f[1] : s[1]);
            float C = isq2 ? s[2] : (isq1 ? f[1] : uu[1]);
            float D = isq2 ? uu[2] : f[2];
            // X1 payload: q0->C, q1->A, q2->D, q3->B   (xor 16)
            float p1 = isq0 ? C : (isq1 ? A : (isq2 ? D : B));
            // X2 payload: q0,q1->B ; q2,q3->C          (xor 48)
            float p2 = (q < 2) ? B : C;
            float r1 = __shfl_xor(p1, 16);
            float r2 = __shfl_xor(p2, 48);
            // owned sums: q0:A+q1.A(bl0)  q1:C+q0.C(bl3)
            //             q2:B+q3.B(bl4)  q3:D+q2.D(bl7)
            float own1 = (isq0 ? A : (isq1 ? C : (isq2 ? B : D))) + r1;
            // owned sums: q0:D+q3.C(bl5)  q1:D+q2.C(bl6)
            //             q2:A+q1.B(bl1)  q3:A+q0.B(bl2)
            float own2 = ((q < 2) ? D : A) + r2;
            out[(size_t)(b0 + blA) * HID + col] = own1 * (1.0f / 6.0f);
            out[(size_t)(b0 + blB) * HID + col] = own2 * (1.0f / 6.0f);
        }
        __syncthreads();   // all a-reads done before next tile's layer-1 stores
    }
}

extern "C" void kernel_launch(void* const* d_in, const int* in_sizes, int n_in,
                              void* d_out, int out_size, void* d_ws, size_t ws_size,
                              hipStream_t stream) {
    // inputs: 0 self_obs (unused), 1 obs, 2 W1, 3 b1, 4 W2, 5 b2, 6/7 scalars
    const float* obs = (const float*)d_in[1];
    const float* W1  = (const float*)d_in[2];
    const float* b1  = (const float*)d_in[3];
    const float* W2  = (const float*)d_in[4];
    const float* b2  = (const float*)d_in[5];
    float* outp = (float*)d_out;

    short* w2t = (short*)d_ws;                       // 131072 B
    short* w1t = (short*)((char*)d_ws + 131072);     // 16384 B

    prep<<<288, 256, 0, stream>>>(W1, W2, w1t, w2t);
    qenc_main<<<GRID_WG, 512, 0, stream>>>(obs, w1t, b1, w2t, b2, outp);
}